// Round 6
// baseline (1258.718 us; speedup 1.0000x reference)
//
#include <hip/hip_runtime.h>

typedef __bf16 bf16x8 __attribute__((ext_vector_type(8)));
typedef float f32x4 __attribute__((ext_vector_type(4)));

#define BETA 0.8f
#define LAM 1e-4f

__device__ __forceinline__ unsigned short f2bf(float x) {
  unsigned u = __float_as_uint(x);
  u += 0x7FFFu + ((u >> 16) & 1u);          // RTNE to bf16
  return (unsigned short)(u >> 16);
}
__device__ __forceinline__ float bf2f(unsigned short h) {
  return __uint_as_float(((unsigned)h) << 16);
}
__device__ __forceinline__ void split2(float x, unsigned short& h, unsigned short& l) {
  h = f2bf(x);
  l = f2bf(x - bf2f(h));
}
__device__ __forceinline__ float fast_tanh(float x) {
  float e = __expf(2.0f * x);
  return 1.0f - 2.0f / (e + 1.0f);
}

__device__ __forceinline__ void async_cp16(const void* g, void* l) {
  __builtin_amdgcn_global_load_lds(
      (const __attribute__((address_space(1))) void*)g,
      (__attribute__((address_space(3))) void*)l, 16, 0, 0);
}

// ---------------------------------------------------------------------------
// bf16x3 GEMM, BK=32, 128x64 tile, 4 waves (2M x 2N), 24KiB LDS.
// R1's measured-conflict-free row layout: 128B = [hi k0..31 | lo k0..31],
// 8x16B slots, XOR-swizzle slot' = slot ^ (row&7) applied on the pre-swizzled
// global source (global_load_lds dest stays linear) and on the ds_read addr.
// Grid = (M/128)*(N/64) = 1024 blocks -> 4 blocks/CU (vs R4's 2): the point
// of this round — more independent barrier groups per SIMD to hide latency.
// MODE 0: gout = acc + bias[n]                      (Xb = x@Wx + b)
// MODE 1: v=tanh(acc+Xb); g=v-zin; u=zin+beta*g; writes g,u
// zin/uout may alias (pointwise same-index, own-tile only) -> NOT __restrict__.
// NOTE: no bf16 u-split writes here — zhi/zlo are this kernel's A input,
// read across the whole block-row by other blocks (cross-block race).
// ---------------------------------------------------------------------------
template<int MODE>
__global__ __launch_bounds__(256, 4)
void gemm_bf16x3(const unsigned short* __restrict__ Ahi,
                 const unsigned short* __restrict__ Alo,
                 const unsigned short* __restrict__ Bhi,
                 const unsigned short* __restrict__ Blo,
                 const float* __restrict__ addv,   // MODE0: bias[n]; MODE1: Xb[m,n]
                 const float* zin,
                 float* __restrict__ gout,
                 float* uout,
                 int M, int N, int K)
{
  __shared__ unsigned short As[128 * 64];   // 16 KiB: 128 rows x 128B
  __shared__ unsigned short Bs[64 * 64];    //  8 KiB:  64 rows x 128B

  const int tid    = threadIdx.x;
  const int lane   = tid & 63;
  const int w      = tid >> 6;
  const int wrow   = w >> 1, wcol = w & 1;
  const int lane15 = lane & 15;
  const int q      = lane >> 4;              // k-quarter 0..3 / C-row group

  // XCD-aware swizzle (grid.x = (M/128)*(N/64), multiple of 8):
  const int nwg = gridDim.x;
  const int bid = blockIdx.x;
  const int sw  = (bid & 7) * (nwg >> 3) + (bid >> 3);
  const int nby = M >> 7;
  const int by  = sw % nby;                  // row-block varies fastest: same
  const int bx  = sw / nby;                  // B column panel stays L2-hot
  const int m0 = by * 128;
  const int n0 = bx * 64;

  // staging: chunk = 8 rows x 128B = 1KB. As: 16 chunks, Bs: 8 chunks.
  const int srow8 = lane >> 3;               // row within chunk (== row&7)
  const int sslot = (lane & 7) ^ srow8;      // pre-swizzled logical slot 0..7
  const int s_hi  = (sslot < 4);
  const int s_ko  = (sslot & 3) * 8;         // k element offset of 16B slot

  f32x4 acc[4][2];
#pragma unroll
  for (int i = 0; i < 4; ++i)
#pragma unroll
    for (int j = 0; j < 2; ++j) acc[i][j] = f32x4{0.f, 0.f, 0.f, 0.f};

  for (int kt = 0; kt < K; kt += 32) {
#pragma unroll
    for (int t = 0; t < 4; ++t) {
      int c   = t * 4 + w;                   // A chunk 0..15
      int row = c * 8 + srow8;               // 0..127
      const unsigned short* sa = (s_hi ? Ahi : Alo)
          + (size_t)(m0 + row) * K + kt + s_ko;
      async_cp16(sa, &As[c * 512]);
    }
#pragma unroll
    for (int t = 0; t < 2; ++t) {
      int c   = t * 4 + w;                   // B chunk 0..7
      int row = c * 8 + srow8;               // 0..63
      const unsigned short* sb = (s_hi ? Bhi : Blo)
          + (size_t)(n0 + row) * K + kt + s_ko;
      async_cp16(sb, &Bs[c * 512]);
    }
    __syncthreads();                         // drains vmcnt + lgkm before use

    bf16x8 ah[4], al[4], bh[2], bl[2];
#pragma unroll
    for (int mi = 0; mi < 4; ++mi) {
      int r = wrow * 64 + mi * 16 + lane15;
      const char* base = (const char*)As + r * 128;
      int swz = (r & 7) << 4;
      ah[mi] = *(const bf16x8*)(base + ((q << 4) ^ swz));
      al[mi] = *(const bf16x8*)(base + ((64 + (q << 4)) ^ swz));
    }
#pragma unroll
    for (int ni = 0; ni < 2; ++ni) {
      int r = wcol * 32 + ni * 16 + lane15;
      const char* base = (const char*)Bs + r * 128;
      int swz = (r & 7) << 4;
      bh[ni] = *(const bf16x8*)(base + ((q << 4) ^ swz));
      bl[ni] = *(const bf16x8*)(base + ((64 + (q << 4)) ^ swz));
    }
#pragma unroll
    for (int mi = 0; mi < 4; ++mi)
#pragma unroll
      for (int ni = 0; ni < 2; ++ni) {
        acc[mi][ni] = __builtin_amdgcn_mfma_f32_16x16x32_bf16(ah[mi], bh[ni], acc[mi][ni], 0, 0, 0);
        acc[mi][ni] = __builtin_amdgcn_mfma_f32_16x16x32_bf16(ah[mi], bl[ni], acc[mi][ni], 0, 0, 0);
        acc[mi][ni] = __builtin_amdgcn_mfma_f32_16x16x32_bf16(al[mi], bh[ni], acc[mi][ni], 0, 0, 0);
      }
    __syncthreads();
  }

  // epilogue: C/D layout col=lane&15, row=(lane>>4)*4+reg  [m89-verified]
#pragma unroll
  for (int mi = 0; mi < 4; ++mi)
#pragma unroll
    for (int ni = 0; ni < 2; ++ni)
#pragma unroll
      for (int j = 0; j < 4; ++j) {
        int m = m0 + wrow * 64 + mi * 16 + q * 4 + j;
        int n = n0 + wcol * 32 + ni * 16 + lane15;
        size_t idx = (size_t)m * N + n;
        float a = acc[mi][ni][j];
        if (MODE == 0) {
          gout[idx] = a + addv[n];
        } else {
          float zv = zin[idx];
          float v  = fast_tanh(a + addv[idx]);
          float gg = v - zv;
          gout[idx] = gg;
          uout[idx] = fmaf(BETA, gg, zv);
        }
      }
}

// --- elementwise / small kernels -------------------------------------------

__global__ void split_rows_k(const float* __restrict__ X, unsigned short* __restrict__ H,
                             unsigned short* __restrict__ L, long n4)
{
  long i = (long)blockIdx.x * blockDim.x + threadIdx.x;
  long stride = (long)gridDim.x * blockDim.x;
  for (; i < n4; i += stride) {
    float4 v = ((const float4*)X)[i];
    ushort4 h, l;
    split2(v.x, h.x, l.x); split2(v.y, h.y, l.y);
    split2(v.z, h.z, l.z); split2(v.w, h.w, l.w);
    ((ushort4*)H)[i] = h; ((ushort4*)L)[i] = l;
  }
}

// W[k][n] -> Th/Tl[n][k]  (split + transpose)
__global__ void split_transpose_k(const float* __restrict__ W,
                                  unsigned short* __restrict__ Th,
                                  unsigned short* __restrict__ Tl, int D)
{
  __shared__ float tile[32][33];
  int n0 = blockIdx.x * 32, k0 = blockIdx.y * 32;
  int tx = threadIdx.x, ty = threadIdx.y;
  for (int r = ty; r < 32; r += 8)
    tile[r][tx] = W[(size_t)(k0 + r) * D + n0 + tx];
  __syncthreads();
  for (int r = ty; r < 32; r += 8) {
    float v = tile[tx][r];
    unsigned short h, l; split2(v, h, l);
    size_t o = (size_t)(n0 + r) * D + k0 + tx;
    Th[o] = h; Tl[o] = l;
  }
}

// i=0: u0 = beta*tanh(Xb)  (z=0 -> g0=tanh(Xb) never needed again); split u0
__global__ void iter0_k(const float* __restrict__ Xb, float* __restrict__ u0,
                        unsigned short* __restrict__ zh,
                        unsigned short* __restrict__ zl, long n4)
{
  long i = (long)blockIdx.x * blockDim.x + threadIdx.x;
  long stride = (long)gridDim.x * blockDim.x;
  for (; i < n4; i += stride) {
    float4 xb = ((const float4*)Xb)[i];
    float4 z;
    z.x = BETA * fast_tanh(xb.x); z.y = BETA * fast_tanh(xb.y);
    z.z = BETA * fast_tanh(xb.z); z.w = BETA * fast_tanh(xb.w);
    ((float4*)u0)[i] = z;
    ushort4 h, l;
    split2(z.x, h.x, l.x); split2(z.y, h.y, l.y);
    split2(z.z, h.z, l.z); split2(z.w, h.w, l.w);
    ((ushort4*)zh)[i] = h; ((ushort4*)zl)[i] = l;
  }
}

// per-row 2x2 gram solve -> gamma[row][2]
__global__ __launch_bounds__(256) void gram_k(const float* __restrict__ g,
                                              const float* __restrict__ gm1,
                                              const float* __restrict__ gm2,
                                              float* __restrict__ gamma, int D)
{
  int row = blockIdx.x;
  const float4* G0 = (const float4*)(g   + (size_t)row * D);
  const float4* G1 = (const float4*)(gm1 + (size_t)row * D);
  const float4* G2 = (const float4*)(gm2 + (size_t)row * D);
  float s00 = 0, s01 = 0, s11 = 0, r0 = 0, r1 = 0;
  int n4 = D >> 2;
  for (int t = threadIdx.x; t < n4; t += 256) {
    float4 a = G0[t], b = G1[t], c = G2[t];
    { float gg = a.x, d0 = gg - b.x, d1 = gg - c.x;
      s00 += d0*d0; s01 += d0*d1; s11 += d1*d1; r0 += d0*gg; r1 += d1*gg; }
    { float gg = a.y, d0 = gg - b.y, d1 = gg - c.y;
      s00 += d0*d0; s01 += d0*d1; s11 += d1*d1; r0 += d0*gg; r1 += d1*gg; }
    { float gg = a.z, d0 = gg - b.z, d1 = gg - c.z;
      s00 += d0*d0; s01 += d0*d1; s11 += d1*d1; r0 += d0*gg; r1 += d1*gg; }
    { float gg = a.w, d0 = gg - b.w, d1 = gg - c.w;
      s00 += d0*d0; s01 += d0*d1; s11 += d1*d1; r0 += d0*gg; r1 += d1*gg; }
  }
  for (int off = 32; off > 0; off >>= 1) {
    s00 += __shfl_down(s00, off); s01 += __shfl_down(s01, off);
    s11 += __shfl_down(s11, off); r0 += __shfl_down(r0, off); r1 += __shfl_down(r1, off);
  }
  __shared__ float red[4][5];
  int lane = threadIdx.x & 63, wv = threadIdx.x >> 6;
  if (lane == 0) { red[wv][0]=s00; red[wv][1]=s01; red[wv][2]=s11; red[wv][3]=r0; red[wv][4]=r1; }
  __syncthreads();
  if (threadIdx.x == 0) {
    s00 = red[0][0]+red[1][0]+red[2][0]+red[3][0];
    s01 = red[0][1]+red[1][1]+red[2][1]+red[3][1];
    s11 = red[0][2]+red[1][2]+red[2][2]+red[3][2];
    r0  = red[0][3]+red[1][3]+red[2][3]+red[3][3];
    r1  = red[0][4]+red[1][4]+red[2][4]+red[3][4];
    float a_ = s00 + LAM, d_ = s11 + LAM, b_ = s01;
    float det = a_ * d_ - b_ * b_ + 1e-8f;
    gamma[row * 2]     = (d_ * r0 - b_ * r1) / det;
    gamma[row * 2 + 1] = (a_ * r1 - b_ * r0) / det;
  }
}

// z_new = uc - (c0*(uc-um1) + c1*(uc-um2)); zn may alias uc/um2 (pointwise).
// Writing zh/zl here is safe: no concurrent reader (stream-ordered consumers).
template<int WSPLIT>
__global__ void anderson_update_k(const float* uc, const float* um1,
                                  const float* um2, const float* __restrict__ gamma,
                                  float* zn, unsigned short* __restrict__ zh,
                                  unsigned short* __restrict__ zl, long n4, int logD4)
{
  long i = (long)blockIdx.x * blockDim.x + threadIdx.x;
  long stride = (long)gridDim.x * blockDim.x;
  for (; i < n4; i += stride) {
    long row = i >> logD4;
    float c0 = gamma[row * 2], c1 = gamma[row * 2 + 1];
    float4 u0 = ((const float4*)uc)[i];
    float4 u1 = ((const float4*)um1)[i];
    float4 u2 = ((const float4*)um2)[i];
    float4 o;
    o.x = u0.x - (c0 * (u0.x - u1.x) + c1 * (u0.x - u2.x));
    o.y = u0.y - (c0 * (u0.y - u1.y) + c1 * (u0.y - u2.y));
    o.z = u0.z - (c0 * (u0.z - u1.z) + c1 * (u0.z - u2.z));
    o.w = u0.w - (c0 * (u0.w - u1.w) + c1 * (u0.w - u2.w));
    ((float4*)zn)[i] = o;
    if (WSPLIT) {
      ushort4 h, l;
      split2(o.x, h.x, l.x); split2(o.y, h.y, l.y);
      split2(o.z, h.z, l.z); split2(o.w, h.w, l.w);
      ((ushort4*)zh)[i] = h; ((ushort4*)zl)[i] = l;
    }
  }
}

// ---------------------------------------------------------------------------

extern "C" void kernel_launch(void* const* d_in, const int* in_sizes, int n_in,
                              void* d_out, int out_size, void* d_ws, size_t ws_size,
                              hipStream_t stream)
{
  const float* x  = (const float*)d_in[0];
  const float* Wz = (const float*)d_in[1];
  const float* Wx = (const float*)d_in[2];
  const float* b  = (const float*)d_in[3];
  const int D = in_sizes[3];
  const int B = in_sizes[0] / D;
  const size_t BD = (size_t)B * D, DD = (size_t)D * D;

  float* Xb  = (float*)d_ws;
  float* gb0 = Xb + BD;
  float* gb1 = gb0 + BD;
  float* gb2 = gb1 + BD;
  float* S0  = gb2 + BD;
  float* S1  = S0 + BD;
  unsigned short* zhi = (unsigned short*)(S1 + BD);
  unsigned short* zlo = zhi + BD;
  unsigned short* Wth = zlo + BD;
  unsigned short* Wtl = Wth + DD;
  float* gamma = (float*)(Wtl + DD);

  // u-history slots: u_i -> S[i%3]; S2 = d_out.  z_i locations:
  //   z1=u0(S0) z2=u1(S1) z3=u2(S2) z4->S1 (upd i=3) z5->S2 (upd i=4) z6->d_out
  float* S[3] = { S0, S1, (float*)d_out };
  float* gslot[3] = { gb0, gb1, gb2 };
  const int zin_i[6] = { 0, 0, 1, 2, 1, 2 };

  dim3 tblk(32, 8);
  dim3 tgrd(D / 32, D / 32);
  int ggrd = (B / 128) * (D / 64);           // 128x64 tiles -> 1024 blocks
  long n4 = (long)(BD >> 2);
  int logD4 = 31 - __builtin_clz((unsigned)(D >> 2));
  const int ebl = 2048;

  // Xb = x @ Wx + b (loop-invariant)
  split_transpose_k<<<tgrd, tblk, 0, stream>>>(Wx, Wth, Wtl, D);
  split_rows_k<<<ebl, 256, 0, stream>>>(x, zhi, zlo, n4);
  gemm_bf16x3<0><<<ggrd, 256, 0, stream>>>(zhi, zlo, Wth, Wtl, b, nullptr,
                                           Xb, nullptr, B, D, D);
  split_transpose_k<<<tgrd, tblk, 0, stream>>>(Wz, Wth, Wtl, D);

  // i=0: u0 = beta*tanh(Xb) = z1, split
  iter0_k<<<ebl, 256, 0, stream>>>(Xb, S[0], zhi, zlo, n4);

  for (int i = 1; i <= 5; ++i) {
    float* zi = S[zin_i[i]];
    float* gi = gslot[i % 3];
    float* ui = S[i % 3];
    gemm_bf16x3<1><<<ggrd, 256, 0, stream>>>(zhi, zlo, Wth, Wtl, Xb, zi,
                                             gi, ui, B, D, D);
    if (i <= 2) {
      // z_{i+1} = u_i: split in a separate stream-ordered kernel (no race
      // with the GEMM that reads zhi/zlo).
      split_rows_k<<<ebl, 256, 0, stream>>>(ui, zhi, zlo, n4);
    } else {
      gram_k<<<B, 256, 0, stream>>>(gi, gslot[(i - 1) % 3], gslot[(i - 2) % 3], gamma, D);
      float* zn = (i == 5) ? (float*)d_out : S[(i + 1) % 3];
      if (i < 5)
        anderson_update_k<1><<<ebl, 256, 0, stream>>>(S[i % 3], S[(i - 1) % 3], S[(i - 2) % 3],
                                                      gamma, zn, zhi, zlo, n4, logD4);
      else
        anderson_update_k<0><<<ebl, 256, 0, stream>>>(S[i % 3], S[(i - 1) % 3], S[(i - 2) % 3],
                                                      gamma, zn, nullptr, nullptr, n4, logD4);
    }
  }
}

// Round 7
// 1081.540 us; speedup vs baseline: 1.1638x; 1.1638x over previous
//
#include <hip/hip_runtime.h>

typedef __bf16 bf16x8 __attribute__((ext_vector_type(8)));
typedef float f32x4 __attribute__((ext_vector_type(4)));

#define BETA 0.8f
#define LAM 1e-4f

__device__ __forceinline__ unsigned short f2bf(float x) {
  unsigned u = __float_as_uint(x);
  u += 0x7FFFu + ((u >> 16) & 1u);          // RTNE to bf16
  return (unsigned short)(u >> 16);
}
__device__ __forceinline__ float bf2f(unsigned short h) {
  return __uint_as_float(((unsigned)h) << 16);
}
__device__ __forceinline__ void split2(float x, unsigned short& h, unsigned short& l) {
  h = f2bf(x);
  l = f2bf(x - bf2f(h));
}
__device__ __forceinline__ float fast_tanh(float x) {
  float e = __expf(2.0f * x);
  return 1.0f - 2.0f / (e + 1.0f);
}

__device__ __forceinline__ void async_cp16(const void* g, void* l) {
  __builtin_amdgcn_global_load_lds(
      (const __attribute__((address_space(1))) void*)g,
      (__attribute__((address_space(3))) void*)l, 16, 0, 0);
}

// ---------------------------------------------------------------------------
// bf16x3 GEMM, BK=32, 128x128 tile, 4 waves 2x2, DOUBLE-buffered 64KiB LDS,
// 2-phase schedule (m248-verified minimum pipeline):
//   prologue: STAGE(buf0); sync;
//   loop:     STAGE(buf^1) -> ds_read/MFMA(buf) -> sync; flip
// One barrier per K-step; the vmcnt(0) drain implied by __syncthreads lands
// after the compute phase, so next-tile loads are already complete.
// Row layout (R1, measured conflict-free): 128B = 8 x 16B logical slots
// [hi k0..31 | lo k0..31], physical slot = logical ^ (row&7), applied on the
// pre-swizzled global source (global_load_lds dest linear) and on ds_read.
// MODE 0: gout = acc + bias[n]                      (Xb = x@Wx + b)
// MODE 1: v=tanh(acc+Xb); g=v-zin; u=zin+beta*g; writes g,u
// zin/uout may alias (pointwise same-index, own-tile only) -> NOT __restrict__.
// NOTE: no bf16 u-split writes here — zhi/zlo are this kernel's A input,
// read across the whole block-row by other blocks (cross-block race).
// ---------------------------------------------------------------------------
template<int MODE>
__global__ __launch_bounds__(256, 2)
void gemm_bf16x3(const unsigned short* __restrict__ Ahi,
                 const unsigned short* __restrict__ Alo,
                 const unsigned short* __restrict__ Bhi,
                 const unsigned short* __restrict__ Blo,
                 const float* __restrict__ addv,   // MODE0: bias[n]; MODE1: Xb[m,n]
                 const float* zin,
                 float* __restrict__ gout,
                 float* uout,
                 int M, int N, int K)
{
  __shared__ unsigned short As[2][128 * 64];   // 2 x 16 KiB
  __shared__ unsigned short Bs[2][128 * 64];   // 2 x 16 KiB

  const int tid    = threadIdx.x;
  const int lane   = tid & 63;
  const int w      = tid >> 6;
  const int wrow   = w >> 1, wcol = w & 1;
  const int lane15 = lane & 15;
  const int q      = lane >> 4;              // k-quarter 0..3 / C-row group

  // XCD-aware swizzle (grid.x = (M/128)*(N/128) = 512, multiple of 8):
  const int nwg = gridDim.x;
  const int bid = blockIdx.x;
  const int sw  = (bid & 7) * (nwg >> 3) + (bid >> 3);
  const int nby = M >> 7;
  const int by  = sw % nby;                  // row-block fastest: B column
  const int bx  = sw / nby;                  // panel stays L2-hot per XCD
  const int m0 = by * 128;
  const int n0 = bx * 128;

  // staging: chunk = 8 rows x 128B = 1KB = 64 lanes x 16B. 16 chunks each.
  const int srow8 = lane >> 3;               // row within chunk (== row&7)
  const int sslot = (lane & 7) ^ srow8;      // pre-swizzled logical slot 0..7
  const int s_hi  = (sslot < 4);
  const int s_ko  = (sslot & 3) * 8;         // k element offset of 16B slot

  f32x4 acc[4][4];
#pragma unroll
  for (int i = 0; i < 4; ++i)
#pragma unroll
    for (int j = 0; j < 4; ++j) acc[i][j] = f32x4{0.f, 0.f, 0.f, 0.f};

  auto stage = [&](int buf, int kt) {
#pragma unroll
    for (int t = 0; t < 4; ++t) {
      int c   = t * 4 + w;                   // chunk 0..15
      int row = c * 8 + srow8;               // 0..127
      const unsigned short* sa = (s_hi ? Ahi : Alo)
          + (size_t)(m0 + row) * K + kt + s_ko;
      async_cp16(sa, &As[buf][c * 512]);
      const unsigned short* sb = (s_hi ? Bhi : Blo)
          + (size_t)(n0 + row) * K + kt + s_ko;
      async_cp16(sb, &Bs[buf][c * 512]);
    }
  };

  auto compute = [&](int buf) {
    bf16x8 ah[4], al[4], bh[4], bl[4];
#pragma unroll
    for (int mi = 0; mi < 4; ++mi) {
      int r = wrow * 64 + mi * 16 + lane15;
      const char* base = (const char*)&As[buf][0] + r * 128;
      int swz = (r & 7) << 4;
      ah[mi] = *(const bf16x8*)(base + ((q << 4) ^ swz));
      al[mi] = *(const bf16x8*)(base + ((64 + (q << 4)) ^ swz));
    }
#pragma unroll
    for (int ni = 0; ni < 4; ++ni) {
      int r = wcol * 64 + ni * 16 + lane15;
      const char* base = (const char*)&Bs[buf][0] + r * 128;
      int swz = (r & 7) << 4;
      bh[ni] = *(const bf16x8*)(base + ((q << 4) ^ swz));
      bl[ni] = *(const bf16x8*)(base + ((64 + (q << 4)) ^ swz));
    }
#pragma unroll
    for (int mi = 0; mi < 4; ++mi)
#pragma unroll
      for (int ni = 0; ni < 4; ++ni) {
        acc[mi][ni] = __builtin_amdgcn_mfma_f32_16x16x32_bf16(ah[mi], bh[ni], acc[mi][ni], 0, 0, 0);
        acc[mi][ni] = __builtin_amdgcn_mfma_f32_16x16x32_bf16(ah[mi], bl[ni], acc[mi][ni], 0, 0, 0);
        acc[mi][ni] = __builtin_amdgcn_mfma_f32_16x16x32_bf16(al[mi], bh[ni], acc[mi][ni], 0, 0, 0);
      }
  };

  // 2-phase pipeline
  stage(0, 0);
  __syncthreads();
  int cur = 0;
  for (int kt = 32; kt < K; kt += 32) {
    stage(cur ^ 1, kt);        // next-tile loads fly during compute below
    compute(cur);
    __syncthreads();           // vmcnt(0)+lgkmcnt(0)+barrier: next buf ready
    cur ^= 1;
  }
  compute(cur);                // last tile, no prefetch

  // epilogue: C/D layout col=lane&15, row=(lane>>4)*4+reg  [m89-verified]
#pragma unroll
  for (int mi = 0; mi < 4; ++mi)
#pragma unroll
    for (int ni = 0; ni < 4; ++ni)
#pragma unroll
      for (int j = 0; j < 4; ++j) {
        int m = m0 + wrow * 64 + mi * 16 + q * 4 + j;
        int n = n0 + wcol * 64 + ni * 16 + lane15;
        size_t idx = (size_t)m * N + n;
        float a = acc[mi][ni][j];
        if (MODE == 0) {
          gout[idx] = a + addv[n];
        } else {
          float zv = zin[idx];
          float v  = fast_tanh(a + addv[idx]);
          float gg = v - zv;
          gout[idx] = gg;
          uout[idx] = fmaf(BETA, gg, zv);
        }
      }
}

// --- elementwise / small kernels -------------------------------------------

__global__ void split_rows_k(const float* __restrict__ X, unsigned short* __restrict__ H,
                             unsigned short* __restrict__ L, long n4)
{
  long i = (long)blockIdx.x * blockDim.x + threadIdx.x;
  long stride = (long)gridDim.x * blockDim.x;
  for (; i < n4; i += stride) {
    float4 v = ((const float4*)X)[i];
    ushort4 h, l;
    split2(v.x, h.x, l.x); split2(v.y, h.y, l.y);
    split2(v.z, h.z, l.z); split2(v.w, h.w, l.w);
    ((ushort4*)H)[i] = h; ((ushort4*)L)[i] = l;
  }
}

// W[k][n] -> Th/Tl[n][k]  (split + transpose)
__global__ void split_transpose_k(const float* __restrict__ W,
                                  unsigned short* __restrict__ Th,
                                  unsigned short* __restrict__ Tl, int D)
{
  __shared__ float tile[32][33];
  int n0 = blockIdx.x * 32, k0 = blockIdx.y * 32;
  int tx = threadIdx.x, ty = threadIdx.y;
  for (int r = ty; r < 32; r += 8)
    tile[r][tx] = W[(size_t)(k0 + r) * D + n0 + tx];
  __syncthreads();
  for (int r = ty; r < 32; r += 8) {
    float v = tile[tx][r];
    unsigned short h, l; split2(v, h, l);
    size_t o = (size_t)(n0 + r) * D + k0 + tx;
    Th[o] = h; Tl[o] = l;
  }
}

// i=0: u0 = beta*tanh(Xb)  (z=0 -> g0=tanh(Xb) never needed again); split u0
__global__ void iter0_k(const float* __restrict__ Xb, float* __restrict__ u0,
                        unsigned short* __restrict__ zh,
                        unsigned short* __restrict__ zl, long n4)
{
  long i = (long)blockIdx.x * blockDim.x + threadIdx.x;
  long stride = (long)gridDim.x * blockDim.x;
  for (; i < n4; i += stride) {
    float4 xb = ((const float4*)Xb)[i];
    float4 z;
    z.x = BETA * fast_tanh(xb.x); z.y = BETA * fast_tanh(xb.y);
    z.z = BETA * fast_tanh(xb.z); z.w = BETA * fast_tanh(xb.w);
    ((float4*)u0)[i] = z;
    ushort4 h, l;
    split2(z.x, h.x, l.x); split2(z.y, h.y, l.y);
    split2(z.z, h.z, l.z); split2(z.w, h.w, l.w);
    ((ushort4*)zh)[i] = h; ((ushort4*)zl)[i] = l;
  }
}

// per-row 2x2 gram solve -> gamma[row][2]
__global__ __launch_bounds__(256) void gram_k(const float* __restrict__ g,
                                              const float* __restrict__ gm1,
                                              const float* __restrict__ gm2,
                                              float* __restrict__ gamma, int D)
{
  int row = blockIdx.x;
  const float4* G0 = (const float4*)(g   + (size_t)row * D);
  const float4* G1 = (const float4*)(gm1 + (size_t)row * D);
  const float4* G2 = (const float4*)(gm2 + (size_t)row * D);
  float s00 = 0, s01 = 0, s11 = 0, r0 = 0, r1 = 0;
  int n4 = D >> 2;
  for (int t = threadIdx.x; t < n4; t += 256) {
    float4 a = G0[t], b = G1[t], c = G2[t];
    { float gg = a.x, d0 = gg - b.x, d1 = gg - c.x;
      s00 += d0*d0; s01 += d0*d1; s11 += d1*d1; r0 += d0*gg; r1 += d1*gg; }
    { float gg = a.y, d0 = gg - b.y, d1 = gg - c.y;
      s00 += d0*d0; s01 += d0*d1; s11 += d1*d1; r0 += d0*gg; r1 += d1*gg; }
    { float gg = a.z, d0 = gg - b.z, d1 = gg - c.z;
      s00 += d0*d0; s01 += d0*d1; s11 += d1*d1; r0 += d0*gg; r1 += d1*gg; }
    { float gg = a.w, d0 = gg - b.w, d1 = gg - c.w;
      s00 += d0*d0; s01 += d0*d1; s11 += d1*d1; r0 += d0*gg; r1 += d1*gg; }
  }
  for (int off = 32; off > 0; off >>= 1) {
    s00 += __shfl_down(s00, off); s01 += __shfl_down(s01, off);
    s11 += __shfl_down(s11, off); r0 += __shfl_down(r0, off); r1 += __shfl_down(r1, off);
  }
  __shared__ float red[4][5];
  int lane = threadIdx.x & 63, wv = threadIdx.x >> 6;
  if (lane == 0) { red[wv][0]=s00; red[wv][1]=s01; red[wv][2]=s11; red[wv][3]=r0; red[wv][4]=r1; }
  __syncthreads();
  if (threadIdx.x == 0) {
    s00 = red[0][0]+red[1][0]+red[2][0]+red[3][0];
    s01 = red[0][1]+red[1][1]+red[2][1]+red[3][1];
    s11 = red[0][2]+red[1][2]+red[2][2]+red[3][2];
    r0  = red[0][3]+red[1][3]+red[2][3]+red[3][3];
    r1  = red[0][4]+red[1][4]+red[2][4]+red[3][4];
    float a_ = s00 + LAM, d_ = s11 + LAM, b_ = s01;
    float det = a_ * d_ - b_ * b_ + 1e-8f;
    gamma[row * 2]     = (d_ * r0 - b_ * r1) / det;
    gamma[row * 2 + 1] = (a_ * r1 - b_ * r0) / det;
  }
}

// z_new = uc - (c0*(uc-um1) + c1*(uc-um2)); zn may alias uc/um2 (pointwise).
// Writing zh/zl here is safe: no concurrent reader (stream-ordered consumers).
template<int WSPLIT>
__global__ void anderson_update_k(const float* uc, const float* um1,
                                  const float* um2, const float* __restrict__ gamma,
                                  float* zn, unsigned short* __restrict__ zh,
                                  unsigned short* __restrict__ zl, long n4, int logD4)
{
  long i = (long)blockIdx.x * blockDim.x + threadIdx.x;
  long stride = (long)gridDim.x * blockDim.x;
  for (; i < n4; i += stride) {
    long row = i >> logD4;
    float c0 = gamma[row * 2], c1 = gamma[row * 2 + 1];
    float4 u0 = ((const float4*)uc)[i];
    float4 u1 = ((const float4*)um1)[i];
    float4 u2 = ((const float4*)um2)[i];
    float4 o;
    o.x = u0.x - (c0 * (u0.x - u1.x) + c1 * (u0.x - u2.x));
    o.y = u0.y - (c0 * (u0.y - u1.y) + c1 * (u0.y - u2.y));
    o.z = u0.z - (c0 * (u0.z - u1.z) + c1 * (u0.z - u2.z));
    o.w = u0.w - (c0 * (u0.w - u1.w) + c1 * (u0.w - u2.w));
    ((float4*)zn)[i] = o;
    if (WSPLIT) {
      ushort4 h, l;
      split2(o.x, h.x, l.x); split2(o.y, h.y, l.y);
      split2(o.z, h.z, l.z); split2(o.w, h.w, l.w);
      ((ushort4*)zh)[i] = h; ((ushort4*)zl)[i] = l;
    }
  }
}

// ---------------------------------------------------------------------------

extern "C" void kernel_launch(void* const* d_in, const int* in_sizes, int n_in,
                              void* d_out, int out_size, void* d_ws, size_t ws_size,
                              hipStream_t stream)
{
  const float* x  = (const float*)d_in[0];
  const float* Wz = (const float*)d_in[1];
  const float* Wx = (const float*)d_in[2];
  const float* b  = (const float*)d_in[3];
  const int D = in_sizes[3];
  const int B = in_sizes[0] / D;
  const size_t BD = (size_t)B * D, DD = (size_t)D * D;

  float* Xb  = (float*)d_ws;
  float* gb0 = Xb + BD;
  float* gb1 = gb0 + BD;
  float* gb2 = gb1 + BD;
  float* S0  = gb2 + BD;
  float* S1  = S0 + BD;
  unsigned short* zhi = (unsigned short*)(S1 + BD);
  unsigned short* zlo = zhi + BD;
  unsigned short* Wth = zlo + BD;
  unsigned short* Wtl = Wth + DD;
  float* gamma = (float*)(Wtl + DD);

  // u-history slots: u_i -> S[i%3]; S2 = d_out.  z_i locations:
  //   z1=u0(S0) z2=u1(S1) z3=u2(S2) z4->S1 (upd i=3) z5->S2 (upd i=4) z6->d_out
  float* S[3] = { S0, S1, (float*)d_out };
  float* gslot[3] = { gb0, gb1, gb2 };
  const int zin_i[6] = { 0, 0, 1, 2, 1, 2 };

  dim3 tblk(32, 8);
  dim3 tgrd(D / 32, D / 32);
  int ggrd = (D / 128) * (B / 128);          // 128x128 tiles -> 512 blocks
  long n4 = (long)(BD >> 2);
  int logD4 = 31 - __builtin_clz((unsigned)(D >> 2));
  const int ebl = 2048;

  // Xb = x @ Wx + b (loop-invariant)
  split_transpose_k<<<tgrd, tblk, 0, stream>>>(Wx, Wth, Wtl, D);
  split_rows_k<<<ebl, 256, 0, stream>>>(x, zhi, zlo, n4);
  gemm_bf16x3<0><<<ggrd, 256, 0, stream>>>(zhi, zlo, Wth, Wtl, b, nullptr,
                                           Xb, nullptr, B, D, D);
  split_transpose_k<<<tgrd, tblk, 0, stream>>>(Wz, Wth, Wtl, D);

  // i=0: u0 = beta*tanh(Xb) = z1, split
  iter0_k<<<ebl, 256, 0, stream>>>(Xb, S[0], zhi, zlo, n4);

  for (int i = 1; i <= 5; ++i) {
    float* zi = S[zin_i[i]];
    float* gi = gslot[i % 3];
    float* ui = S[i % 3];
    gemm_bf16x3<1><<<ggrd, 256, 0, stream>>>(zhi, zlo, Wth, Wtl, Xb, zi,
                                             gi, ui, B, D, D);
    if (i <= 2) {
      // z_{i+1} = u_i: split in a separate stream-ordered kernel (no race
      // with the GEMM that reads zhi/zlo).
      split_rows_k<<<ebl, 256, 0, stream>>>(ui, zhi, zlo, n4);
    } else {
      gram_k<<<B, 256, 0, stream>>>(gi, gslot[(i - 1) % 3], gslot[(i - 2) % 3], gamma, D);
      float* zn = (i == 5) ? (float*)d_out : S[(i + 1) % 3];
      if (i < 5)
        anderson_update_k<1><<<ebl, 256, 0, stream>>>(S[i % 3], S[(i - 1) % 3], S[(i - 2) % 3],
                                                      gamma, zn, zhi, zlo, n4, logD4);
      else
        anderson_update_k<0><<<ebl, 256, 0, stream>>>(S[i % 3], S[(i - 1) % 3], S[(i - 2) % 3],
                                                      gamma, zn, nullptr, nullptr, n4, logD4);
    }
  }
}

// Round 9
// 1046.475 us; speedup vs baseline: 1.2028x; 1.0335x over previous
//
#include <hip/hip_runtime.h>

typedef __bf16 bf16x8 __attribute__((ext_vector_type(8)));
typedef float f32x4 __attribute__((ext_vector_type(4)));

#define BETA 0.8f
#define LAM 1e-4f

__device__ __forceinline__ unsigned short f2bf(float x) {
  unsigned u = __float_as_uint(x);
  u += 0x7FFFu + ((u >> 16) & 1u);          // RTNE to bf16
  return (unsigned short)(u >> 16);
}
__device__ __forceinline__ float bf2f(unsigned short h) {
  return __uint_as_float(((unsigned)h) << 16);
}
__device__ __forceinline__ void split2(float x, unsigned short& h, unsigned short& l) {
  h = f2bf(x);
  l = f2bf(x - bf2f(h));
}
__device__ __forceinline__ float fast_tanh(float x) {
  float e = __expf(2.0f * x);
  return 1.0f - 2.0f / (e + 1.0f);
}

__device__ __forceinline__ void async_cp16(const void* g, void* l) {
  __builtin_amdgcn_global_load_lds(
      (const __attribute__((address_space(1))) void*)g,
      (__attribute__((address_space(3))) void*)l, 16, 0, 0);
}

typedef unsigned short lds_tile_t[128 * 64];   // 16 KiB: 128 rows x 128B

// ---------------------------------------------------------------------------
// bf16x3 GEMM, BK=32, 128x128 tile, 4 waves 2x2, double-buffered 64KiB LDS.
// 2-phase schedule with STATICALLY-NAMED buffers (R7 lesson: runtime buf
// index defeats alias analysis -> compiler drains vmcnt before ds_read;
// named As0/As1 + forceinline helpers give compile-time provenance, so the
// only drain is inside __syncthreads, landing AFTER the compute phase):
//   stage(buf0); sync;
//   loop x2-unrolled: stage(buf1) -> compute(buf0) -> sync
//                     stage(buf0) -> compute(buf1) -> sync
// Row layout (R1, measured conflict-free): 128B = 8 x 16B logical slots
// [hi k0..31 | lo k0..31], physical slot = logical ^ (row&7), applied on the
// pre-swizzled global source (global_load_lds dest linear) and on ds_read.
// MODE 0: gout = acc + bias[n]                      (Xb = x@Wx + b)
// MODE 1: v=tanh(acc+Xb); g=v-zin; u=zin+beta*g; writes g,u
// ---------------------------------------------------------------------------

__device__ __forceinline__ void stage_step(
    lds_tile_t& As, lds_tile_t& Bs,
    const unsigned short* __restrict__ Ahi, const unsigned short* __restrict__ Alo,
    const unsigned short* __restrict__ Bhi, const unsigned short* __restrict__ Blo,
    int m0, int n0, int kt, int K, int w, int srow8, int s_hi, int s_ko)
{
#pragma unroll
  for (int t = 0; t < 4; ++t) {
    int c   = t * 4 + w;                   // chunk 0..15
    int row = c * 8 + srow8;               // 0..127
    const unsigned short* sa = (s_hi ? Ahi : Alo)
        + (size_t)(m0 + row) * K + kt + s_ko;
    async_cp16(sa, &As[c * 512]);
    const unsigned short* sb = (s_hi ? Bhi : Blo)
        + (size_t)(n0 + row) * K + kt + s_ko;
    async_cp16(sb, &Bs[c * 512]);
  }
}

__device__ __forceinline__ void compute_step(
    const lds_tile_t& As, const lds_tile_t& Bs, f32x4 (&acc)[4][4],
    int wrow, int wcol, int lane15, int q)
{
  bf16x8 ah[4], al[4], bh[4], bl[4];
#pragma unroll
  for (int mi = 0; mi < 4; ++mi) {
    int r = wrow * 64 + mi * 16 + lane15;
    const char* base = (const char*)&As[0] + r * 128;
    int swz = (r & 7) << 4;
    ah[mi] = *(const bf16x8*)(base + ((q << 4) ^ swz));
    al[mi] = *(const bf16x8*)(base + ((64 + (q << 4)) ^ swz));
  }
#pragma unroll
  for (int ni = 0; ni < 4; ++ni) {
    int r = wcol * 64 + ni * 16 + lane15;
    const char* base = (const char*)&Bs[0] + r * 128;
    int swz = (r & 7) << 4;
    bh[ni] = *(const bf16x8*)(base + ((q << 4) ^ swz));
    bl[ni] = *(const bf16x8*)(base + ((64 + (q << 4)) ^ swz));
  }
#pragma unroll
  for (int mi = 0; mi < 4; ++mi)
#pragma unroll
    for (int ni = 0; ni < 4; ++ni) {
      acc[mi][ni] = __builtin_amdgcn_mfma_f32_16x16x32_bf16(ah[mi], bh[ni], acc[mi][ni], 0, 0, 0);
      acc[mi][ni] = __builtin_amdgcn_mfma_f32_16x16x32_bf16(ah[mi], bl[ni], acc[mi][ni], 0, 0, 0);
      acc[mi][ni] = __builtin_amdgcn_mfma_f32_16x16x32_bf16(al[mi], bh[ni], acc[mi][ni], 0, 0, 0);
    }
}

template<int MODE>
__global__ __launch_bounds__(256, 2)
void gemm_bf16x3(const unsigned short* __restrict__ Ahi,
                 const unsigned short* __restrict__ Alo,
                 const unsigned short* __restrict__ Bhi,
                 const unsigned short* __restrict__ Blo,
                 const float* __restrict__ addv,   // MODE0: bias[n]; MODE1: Xb[m,n]
                 const float* zin,
                 float* __restrict__ gout,
                 float* uout,
                 int M, int N, int K)
{
  __shared__ lds_tile_t As0, Bs0, As1, Bs1;  // 4 x 16 KiB, statically named

  const int tid    = threadIdx.x;
  const int lane   = tid & 63;
  const int w      = tid >> 6;
  const int wrow   = w >> 1, wcol = w & 1;
  const int lane15 = lane & 15;
  const int q      = lane >> 4;              // k-quarter 0..3 / C-row group

  // XCD-aware swizzle (grid.x = (M/128)*(N/128) = 512, multiple of 8):
  const int nwg = gridDim.x;
  const int bid = blockIdx.x;
  const int sw  = (bid & 7) * (nwg >> 3) + (bid >> 3);
  const int nby = M >> 7;
  const int by  = sw % nby;                  // row-block fastest: B column
  const int bx  = sw / nby;                  // panel stays L2-hot per XCD
  const int m0 = by * 128;
  const int n0 = bx * 128;

  // staging: chunk = 8 rows x 128B = 1KB = 64 lanes x 16B. 16 chunks each.
  const int srow8 = lane >> 3;               // row within chunk (== row&7)
  const int sslot = (lane & 7) ^ srow8;      // pre-swizzled logical slot 0..7
  const int s_hi  = (sslot < 4);
  const int s_ko  = (sslot & 3) * 8;         // k element offset of 16B slot

  f32x4 acc[4][4];
#pragma unroll
  for (int i = 0; i < 4; ++i)
#pragma unroll
    for (int j = 0; j < 4; ++j) acc[i][j] = f32x4{0.f, 0.f, 0.f, 0.f};

  // 2-phase pipeline, x2-unrolled over statically named buffers (K % 64 == 0)
  stage_step(As0, Bs0, Ahi, Alo, Bhi, Blo, m0, n0, 0, K, w, srow8, s_hi, s_ko);
  __syncthreads();
  for (int kt = 0; kt < K; kt += 64) {
    stage_step(As1, Bs1, Ahi, Alo, Bhi, Blo, m0, n0, kt + 32, K, w, srow8, s_hi, s_ko);
    compute_step(As0, Bs0, acc, wrow, wcol, lane15, q);
    __syncthreads();                         // drain lands after compute
    if (kt + 64 < K)
      stage_step(As0, Bs0, Ahi, Alo, Bhi, Blo, m0, n0, kt + 64, K, w, srow8, s_hi, s_ko);
    compute_step(As1, Bs1, acc, wrow, wcol, lane15, q);
    __syncthreads();
  }

  // epilogue: C/D layout col=lane&15, row=(lane>>4)*4+reg  [m89-verified]
#pragma unroll
  for (int mi = 0; mi < 4; ++mi)
#pragma unroll
    for (int ni = 0; ni < 4; ++ni)
#pragma unroll
      for (int j = 0; j < 4; ++j) {
        int m = m0 + wrow * 64 + mi * 16 + q * 4 + j;
        int n = n0 + wcol * 64 + ni * 16 + lane15;
        size_t idx = (size_t)m * N + n;
        float a = acc[mi][ni][j];
        if (MODE == 0) {
          gout[idx] = a + addv[n];
        } else {
          float zv = zin[idx];
          float v  = fast_tanh(a + addv[idx]);
          float gg = v - zv;
          gout[idx] = gg;
          uout[idx] = fmaf(BETA, gg, zv);
        }
      }
}

// --- elementwise / small kernels -------------------------------------------

__global__ void split_rows_k(const float* __restrict__ X, unsigned short* __restrict__ H,
                             unsigned short* __restrict__ L, long n4)
{
  long i = (long)blockIdx.x * blockDim.x + threadIdx.x;
  long stride = (long)gridDim.x * blockDim.x;
  for (; i < n4; i += stride) {
    float4 v = ((const float4*)X)[i];
    ushort4 h, l;
    split2(v.x, h.x, l.x); split2(v.y, h.y, l.y);
    split2(v.z, h.z, l.z); split2(v.w, h.w, l.w);
    ((ushort4*)H)[i] = h; ((ushort4*)L)[i] = l;
  }
}

// W[k][n] -> Th/Tl[n][k]  (split + transpose)
__global__ void split_transpose_k(const float* __restrict__ W,
                                  unsigned short* __restrict__ Th,
                                  unsigned short* __restrict__ Tl, int D)
{
  __shared__ float tile[32][33];
  int n0 = blockIdx.x * 32, k0 = blockIdx.y * 32;
  int tx = threadIdx.x, ty = threadIdx.y;
  for (int r = ty; r < 32; r += 8)
    tile[r][tx] = W[(size_t)(k0 + r) * D + n0 + tx];
  __syncthreads();
  for (int r = ty; r < 32; r += 8) {
    float v = tile[tx][r];
    unsigned short h, l; split2(v, h, l);
    size_t o = (size_t)(n0 + r) * D + k0 + tx;
    Th[o] = h; Tl[o] = l;
  }
}

// i=0: u0 = beta*tanh(Xb)  (z=0 -> g0=tanh(Xb) never needed again); split u0
__global__ void iter0_k(const float* __restrict__ Xb, float* __restrict__ u0,
                        unsigned short* __restrict__ zh,
                        unsigned short* __restrict__ zl, long n4)
{
  long i = (long)blockIdx.x * blockDim.x + threadIdx.x;
  long stride = (long)gridDim.x * blockDim.x;
  for (; i < n4; i += stride) {
    float4 xb = ((const float4*)Xb)[i];
    float4 z;
    z.x = BETA * fast_tanh(xb.x); z.y = BETA * fast_tanh(xb.y);
    z.z = BETA * fast_tanh(xb.z); z.w = BETA * fast_tanh(xb.w);
    ((float4*)u0)[i] = z;
    ushort4 h, l;
    split2(z.x, h.x, l.x); split2(z.y, h.y, l.y);
    split2(z.z, h.z, l.z); split2(z.w, h.w, l.w);
    ((ushort4*)zh)[i] = h; ((ushort4*)zl)[i] = l;
  }
}

// per-row 2x2 gram solve -> gamma[row][2]
__global__ __launch_bounds__(256) void gram_k(const float* __restrict__ g,
                                              const float* __restrict__ gm1,
                                              const float* __restrict__ gm2,
                                              float* __restrict__ gamma, int D)
{
  int row = blockIdx.x;
  const float4* G0 = (const float4*)(g   + (size_t)row * D);
  const float4* G1 = (const float4*)(gm1 + (size_t)row * D);
  const float4* G2 = (const float4*)(gm2 + (size_t)row * D);
  float s00 = 0, s01 = 0, s11 = 0, r0 = 0, r1 = 0;
  int n4 = D >> 2;
  for (int t = threadIdx.x; t < n4; t += 256) {
    float4 a = G0[t], b = G1[t], c = G2[t];
    { float gg = a.x, d0 = gg - b.x, d1 = gg - c.x;
      s00 += d0*d0; s01 += d0*d1; s11 += d1*d1; r0 += d0*gg; r1 += d1*gg; }
    { float gg = a.y, d0 = gg - b.y, d1 = gg - c.y;
      s00 += d0*d0; s01 += d0*d1; s11 += d1*d1; r0 += d0*gg; r1 += d1*gg; }
    { float gg = a.z, d0 = gg - b.z, d1 = gg - c.z;
      s00 += d0*d0; s01 += d0*d1; s11 += d1*d1; r0 += d0*gg; r1 += d1*gg; }
    { float gg = a.w, d0 = gg - b.w, d1 = gg - c.w;
      s00 += d0*d0; s01 += d0*d1; s11 += d1*d1; r0 += d0*gg; r1 += d1*gg; }
  }
  for (int off = 32; off > 0; off >>= 1) {
    s00 += __shfl_down(s00, off); s01 += __shfl_down(s01, off);
    s11 += __shfl_down(s11, off); r0 += __shfl_down(r0, off); r1 += __shfl_down(r1, off);
  }
  __shared__ float red[4][5];
  int lane = threadIdx.x & 63, wv = threadIdx.x >> 6;
  if (lane == 0) { red[wv][0]=s00; red[wv][1]=s01; red[wv][2]=s11; red[wv][3]=r0; red[wv][4]=r1; }
  __syncthreads();
  if (threadIdx.x == 0) {
    s00 = red[0][0]+red[1][0]+red[2][0]+red[3][0];
    s01 = red[0][1]+red[1][1]+red[2][1]+red[3][1];
    s11 = red[0][2]+red[1][2]+red[2][2]+red[3][2];
    r0  = red[0][3]+red[1][3]+red[2][3]+red[3][3];
    r1  = red[0][4]+red[1][4]+red[2][4]+red[3][4];
    float a_ = s00 + LAM, d_ = s11 + LAM, b_ = s01;
    float det = a_ * d_ - b_ * b_ + 1e-8f;
    gamma[row * 2]     = (d_ * r0 - b_ * r1) / det;
    gamma[row * 2 + 1] = (a_ * r1 - b_ * r0) / det;
  }
}

// z_new = uc - (c0*(uc-um1) + c1*(uc-um2)); zn may alias uc/um2 (pointwise).
// Writing zh/zl here is safe: no concurrent reader (stream-ordered consumers).
template<int WSPLIT>
__global__ void anderson_update_k(const float* uc, const float* um1,
                                  const float* um2, const float* __restrict__ gamma,
                                  float* zn, unsigned short* __restrict__ zh,
                                  unsigned short* __restrict__ zl, long n4, int logD4)
{
  long i = (long)blockIdx.x * blockDim.x + threadIdx.x;
  long stride = (long)gridDim.x * blockDim.x;
  for (; i < n4; i += stride) {
    long row = i >> logD4;
    float c0 = gamma[row * 2], c1 = gamma[row * 2 + 1];
    float4 u0 = ((const float4*)uc)[i];
    float4 u1 = ((const float4*)um1)[i];
    float4 u2 = ((const float4*)um2)[i];
    float4 o;
    o.x = u0.x - (c0 * (u0.x - u1.x) + c1 * (u0.x - u2.x));
    o.y = u0.y - (c0 * (u0.y - u1.y) + c1 * (u0.y - u2.y));
    o.z = u0.z - (c0 * (u0.z - u1.z) + c1 * (u0.z - u2.z));
    o.w = u0.w - (c0 * (u0.w - u1.w) + c1 * (u0.w - u2.w));
    ((float4*)zn)[i] = o;
    if (WSPLIT) {
      ushort4 h, l;
      split2(o.x, h.x, l.x); split2(o.y, h.y, l.y);
      split2(o.z, h.z, l.z); split2(o.w, h.w, l.w);
      ((ushort4*)zh)[i] = h; ((ushort4*)zl)[i] = l;
    }
  }
}

// ---------------------------------------------------------------------------

extern "C" void kernel_launch(void* const* d_in, const int* in_sizes, int n_in,
                              void* d_out, int out_size, void* d_ws, size_t ws_size,
                              hipStream_t stream)
{
  const float* x  = (const float*)d_in[0];
  const float* Wz = (const float*)d_in[1];
  const float* Wx = (const float*)d_in[2];
  const float* b  = (const float*)d_in[3];
  const int D = in_sizes[3];
  const int B = in_sizes[0] / D;
  const size_t BD = (size_t)B * D, DD = (size_t)D * D;

  float* Xb  = (float*)d_ws;
  float* gb0 = Xb + BD;
  float* gb1 = gb0 + BD;
  float* gb2 = gb1 + BD;
  float* S0  = gb2 + BD;
  float* S1  = S0 + BD;
  unsigned short* zhi = (unsigned short*)(S1 + BD);
  unsigned short* zlo = zhi + BD;
  unsigned short* Wth = zlo + BD;
  unsigned short* Wtl = Wth + DD;
  float* gamma = (float*)(Wtl + DD);

  // u-history slots: u_i -> S[i%3]; S2 = d_out.  z_i locations:
  //   z1=u0(S0) z2=u1(S1) z3=u2(S2) z4->S1 (upd i=3) z5->S2 (upd i=4) z6->d_out
  float* S[3] = { S0, S1, (float*)d_out };
  float* gslot[3] = { gb0, gb1, gb2 };
  const int zin_i[6] = { 0, 0, 1, 2, 1, 2 };

  dim3 tblk(32, 8);
  dim3 tgrd(D / 32, D / 32);
  int ggrd = (D / 128) * (B / 128);          // 128x128 tiles -> 512 blocks
  long n4 = (long)(BD >> 2);
  int logD4 = 31 - __builtin_clz((unsigned)(D >> 2));
  const int ebl = 2048;

  // Xb = x @ Wx + b (loop-invariant)
  split_transpose_k<<<tgrd, tblk, 0, stream>>>(Wx, Wth, Wtl, D);
  split_rows_k<<<ebl, 256, 0, stream>>>(x, zhi, zlo, n4);
  gemm_bf16x3<0><<<ggrd, 256, 0, stream>>>(zhi, zlo, Wth, Wtl, b, nullptr,
                                           Xb, nullptr, B, D, D);
  split_transpose_k<<<tgrd, tblk, 0, stream>>>(Wz, Wth, Wtl, D);

  // i=0: u0 = beta*tanh(Xb) = z1, split
  iter0_k<<<ebl, 256, 0, stream>>>(Xb, S[0], zhi, zlo, n4);

  for (int i = 1; i <= 5; ++i) {
    float* zi = S[zin_i[i]];
    float* gi = gslot[i % 3];
    float* ui = S[i % 3];
    gemm_bf16x3<1><<<ggrd, 256, 0, stream>>>(zhi, zlo, Wth, Wtl, Xb, zi,
                                             gi, ui, B, D, D);
    if (i <= 2) {
      // z_{i+1} = u_i: split in a separate stream-ordered kernel (no race
      // with the GEMM that reads zhi/zlo).
      split_rows_k<<<ebl, 256, 0, stream>>>(ui, zhi, zlo, n4);
    } else {
      gram_k<<<B, 256, 0, stream>>>(gi, gslot[(i - 1) % 3], gslot[(i - 2) % 3], gamma, D);
      float* zn = (i == 5) ? (float*)d_out : S[(i + 1) % 3];
      if (i < 5)
        anderson_update_k<1><<<ebl, 256, 0, stream>>>(S[i % 3], S[(i - 1) % 3], S[(i - 2) % 3],
                                                      gamma, zn, zhi, zlo, n4, logD4);
      else
        anderson_update_k<0><<<ebl, 256, 0, stream>>>(S[i % 3], S[(i - 1) % 3], S[(i - 2) % 3],
                                                      gamma, zn, nullptr, nullptr, n4, logD4);
    }
  }
}